// Round 1
// baseline (567.215 us; speedup 1.0000x reference)
//
#include <hip/hip_runtime.h>

#define B_ 16
#define N_ 2048
#define M_ 2048
#define ROWS 32    // rows per block (band)
#define WROWS 8    // rows per wave (4 waves/block)
#define KCAP 2     // sparse-capture capacity per row (overflow -> dense fallback)

__device__ __forceinline__ float wave_sum(float v) {
#pragma unroll
    for (int off = 32; off >= 1; off >>= 1) v += __shfl_xor(v, off);
    return v;
}

// Pass 1 (fused): col_gt/col_cnt column partials + row-local src_neg/src_pos
// computed inline from a register-cached row, + sparse capture of nonzero g.
extern "C" __global__ __launch_bounds__(256) void k_pass1(
    const float* __restrict__ pred, const float* __restrict__ gt,
    const int* __restrict__ src_ns, const int* __restrict__ tgt_ns,
    const float* __restrict__ beta_p,
    float* __restrict__ col_gt, float* __restrict__ col_cnt,
    float* __restrict__ src_neg, float* __restrict__ src_pos,
    int* __restrict__ nnz, int* __restrict__ ent_col,
    float* __restrict__ ent_val, int* flag)
{
    const int b = blockIdx.y;
    const int src = src_ns[b];
    const int band = blockIdx.x;
    if (band * ROWS >= src) return;   // whole band masked out (block-uniform)
    const int tgt = tgt_ns[b];
    const float beta = beta_p[0];
    const int wave = threadIdx.x >> 6, lane = threadIdx.x & 63;
    const int base = b * (N_ * M_);

    float4 acg[8], accn[8];
#pragma unroll
    for (int j = 0; j < 8; ++j) { acg[j] = make_float4(0,0,0,0); accn[j] = make_float4(0,0,0,0); }

    const int row0 = band * ROWS + wave * WROWS;
    for (int r = 0; r < WROWS; ++r) {
        const int n = row0 + r;
        if (n >= src) break;          // rows ascending; wave-uniform
        const int ri = b * N_ + n;
        const float4* prow = (const float4*)(pred + base + n * M_);
        const float4* grow = (const float4*)(gt + base + n * M_);
        float rg = 0.f, rc = 0.f;
        float4 pr[8], gr[8];
#pragma unroll
        for (int j = 0; j < 8; ++j) {
            const int m4 = j * 64 + lane;
            float4 p4 = prow[m4];
            float4 g4 = grow[m4];
            const int mb = m4 * 4;
#define P1C(KK, MB) do { \
    const int c = mb + KK; \
    const bool ok = c < tgt; \
    float p = fminf(fmaxf(p4.MB, 0.f), 1.f); p = ok ? p : 0.f; \
    const float gv = ok ? g4.MB : 0.f; \
    const float gp = p * gv; \
    rg += gp; rc += gv; \
    acg[j].MB += gp; accn[j].MB += gv; \
    p4.MB = p; g4.MB = gv; \
    if (gv != 0.f) { \
        const int slot = atomicAdd(&nnz[ri], 1); \
        if (slot < KCAP) { ent_col[ri * KCAP + slot] = c; ent_val[ri * KCAP + slot] = gv; } \
        else *flag = 1; \
    } \
} while (0)
            P1C(0, x); P1C(1, y); P1C(2, z); P1C(3, w);
#undef P1C
            pr[j] = p4; gr[j] = g4;
        }
        rg = wave_sum(rg); rc = wave_sum(rc);
        const float rth = rg - beta;
        // row-local src_neg/src_pos straight from the register-cached row.
        // masked elements have p==0 -> ds==0 and gp==0 regardless of 'as'.
        float sneg = 0.f, spos = 0.f;
#pragma unroll
        for (int j = 0; j < 8; ++j) {
#define P1S(MB) do { \
    const float p = pr[j].MB; const float gv = gr[j].MB; \
    const float as = (p >= rth) ? rc : 0.f; \
    const float ds = (as - gv) * p; \
    sneg += ds * ds; \
    const float gp = gv * p; spos += gp * gp; \
} while (0)
            P1S(x); P1S(y); P1S(z); P1S(w);
#undef P1S
        }
        sneg = wave_sum(sneg); spos = wave_sum(spos);
        if (lane == 0) { src_neg[ri] = sneg; src_pos[ri] = spos; }
    }

    // combine column partials across the 4 waves in LDS (sequential rounds)
    __shared__ float4 s_cg[M_ / 4];
    __shared__ float4 s_cc[M_ / 4];
    for (int i = threadIdx.x; i < M_ / 4; i += 256) {
        s_cg[i] = make_float4(0,0,0,0);
        s_cc[i] = make_float4(0,0,0,0);
    }
    __syncthreads();
    for (int w = 0; w < 4; ++w) {
        if (wave == w) {
#pragma unroll
            for (int j = 0; j < 8; ++j) {
                const int i = j * 64 + lane;
                float4 v = s_cg[i];
                v.x += acg[j].x; v.y += acg[j].y; v.z += acg[j].z; v.w += acg[j].w;
                s_cg[i] = v;
                float4 u = s_cc[i];
                u.x += accn[j].x; u.y += accn[j].y; u.z += accn[j].z; u.w += accn[j].w;
                s_cc[i] = u;
            }
        }
        __syncthreads();
    }
    const float* fcg = (const float*)s_cg;
    const float* fcc = (const float*)s_cc;
    for (int i = threadIdx.x; i < M_; i += 256) {
        atomicAdd(&col_gt[b * M_ + i], fcg[i]);
        atomicAdd(&col_cnt[b * M_ + i], fcc[i]);
    }
}

// Pass 2: tgt_neg column reduction. Sparse path reads ONLY pred (g
// reconstructed from pass1's capture, exact corrections via per-entry
// atomics). Dense fallback (flag set) reads gt like the original.
extern "C" __global__ __launch_bounds__(256) void k_pass2(
    const float* __restrict__ pred, const float* __restrict__ gt,
    const int* __restrict__ src_ns, const int* __restrict__ tgt_ns,
    const float* __restrict__ beta_p,
    const float* __restrict__ col_gt, const float* __restrict__ col_cnt,
    const int* __restrict__ nnz, const int* __restrict__ ent_col,
    const float* __restrict__ ent_val, const int* flag,
    float* __restrict__ tgt_neg)
{
    const int b = blockIdx.y;
    const int src = src_ns[b];
    const int band = blockIdx.x;
    if (band * ROWS >= src) return;
    const int tgt = tgt_ns[b];
    const float beta = beta_p[0];
    const int wave = threadIdx.x >> 6, lane = threadIdx.x & 63;
    const int base = b * (N_ * M_);
    const bool dense = (*flag != 0);

    float4 cg[8], cc[8], tn[8];
    const float4* cg4 = (const float4*)(col_gt + b * M_);
    const float4* cc4 = (const float4*)(col_cnt + b * M_);
#pragma unroll
    for (int j = 0; j < 8; ++j) {
        cg[j] = cg4[j * 64 + lane];
        cc[j] = cc4[j * 64 + lane];
        tn[j] = make_float4(0,0,0,0);
    }

    const int row0 = band * ROWS + wave * WROWS;
    if (!dense) {
        for (int r = 0; r < WROWS; ++r) {
            const int n = row0 + r;
            if (n >= src) break;
            const float4* prow = (const float4*)(pred + base + n * M_);
#pragma unroll
            for (int j = 0; j < 8; ++j) {
                const int m4 = j * 64 + lane;
                const float4 p4 = prow[m4];
                const int mb = m4 * 4;
#define P2S(KK, MB) do { \
    const bool ok = (mb + KK) < tgt; \
    float p = fminf(fmaxf(p4.MB, 0.f), 1.f); p = ok ? p : 0.f; \
    const float at = (p >= cg[j].MB - beta) ? cc[j].MB : 0.f; \
    const float d = at * p; \
    tn[j].MB += d * d; \
} while (0)
                P2S(0, x); P2S(1, y); P2S(2, z); P2S(3, w);
#undef P2S
            }
            // exact corrections at the (few) nonzero-g positions
            const int ri = b * N_ + n;
            const int nn = nnz[ri];
            if (nn > 0 && lane == 0) {
                const int ne = nn < KCAP ? nn : KCAP;
                for (int s = 0; s < ne; ++s) {
                    const int c = ent_col[ri * KCAP + s];   // c < tgt by capture
                    const float gv = ent_val[ri * KCAP + s];
                    float pv = pred[base + n * M_ + c];
                    pv = fminf(fmaxf(pv, 0.f), 1.f);
                    const float at = (pv >= col_gt[b * M_ + c] - beta) ? col_cnt[b * M_ + c] : 0.f;
                    const float d0 = at * pv;
                    const float d1 = (at - gv) * pv;
                    atomicAdd(&tgt_neg[b * M_ + c], d1 * d1 - d0 * d0);
                }
            }
        }
    } else {
        for (int r = 0; r < WROWS; ++r) {
            const int n = row0 + r;
            if (n >= src) break;
            const float4* prow = (const float4*)(pred + base + n * M_);
            const float4* grow = (const float4*)(gt + base + n * M_);
#pragma unroll
            for (int j = 0; j < 8; ++j) {
                const int m4 = j * 64 + lane;
                const float4 p4 = prow[m4];
                const float4 g4 = grow[m4];
                const int mb = m4 * 4;
#define P2D(KK, MB) do { \
    const bool ok = (mb + KK) < tgt; \
    float p = fminf(fmaxf(p4.MB, 0.f), 1.f); p = ok ? p : 0.f; \
    const float gv = ok ? g4.MB : 0.f; \
    const float at = (ok && (p >= cg[j].MB - beta)) ? cc[j].MB : 0.f; \
    const float dt = (at - gv) * p; \
    tn[j].MB += dt * dt; \
} while (0)
                P2D(0, x); P2D(1, y); P2D(2, z); P2D(3, w);
#undef P2D
            }
        }
    }

    __shared__ float4 s_tn[M_ / 4];
    for (int i = threadIdx.x; i < M_ / 4; i += 256) s_tn[i] = make_float4(0,0,0,0);
    __syncthreads();
    for (int w = 0; w < 4; ++w) {
        if (wave == w) {
#pragma unroll
            for (int j = 0; j < 8; ++j) {
                const int i = j * 64 + lane;
                float4 v = s_tn[i];
                v.x += tn[j].x; v.y += tn[j].y; v.z += tn[j].z; v.w += tn[j].w;
                s_tn[i] = v;
            }
        }
        __syncthreads();
    }
    const float* ftn = (const float*)s_tn;
    for (int i = threadIdx.x; i < M_; i += 256)
        atomicAdd(&tgt_neg[b * M_ + i], ftn[i]);
}

// Final: corr[b] = dot(tgt_neg, col_cnt), then loss reduction -> single scalar
extern "C" __global__ __launch_bounds__(256) void k_final(
    const float* __restrict__ src_neg, const float* __restrict__ src_pos,
    const float* __restrict__ tgt_neg, const float* __restrict__ col_cnt,
    const int* __restrict__ src_ns, float* __restrict__ out)
{
    const int b = blockIdx.x;
    const int wave = threadIdx.x >> 6, lane = threadIdx.x & 63;
    __shared__ float sredc[4];
    __shared__ float sredl[4];

    float c = 0.f;
    for (int i = threadIdx.x; i < M_; i += 256)
        c += tgt_neg[b * M_ + i] * col_cnt[b * M_ + i];
    c = wave_sum(c);
    if (lane == 0) sredc[wave] = c;
    __syncthreads();
    const float corr = sredc[0] + sredc[1] + sredc[2] + sredc[3];

    const int src = src_ns[b];
    float ls = 0.f;
    for (int n = threadIdx.x; n < src; n += 256) {
        const float sp = src_pos[b * N_ + n];
        const float sn = src_neg[b * N_ + n];
        ls += logf(sp) - logf(1.f + sn + corr);
    }
    ls = wave_sum(ls);
    if (lane == 0) sredl[wave] = ls;
    __syncthreads();
    if (threadIdx.x == 0) {
        const float total = sredl[0] + sredl[1] + sredl[2] + sredl[3];
        float nsum = 0.f;
        for (int i = 0; i < B_; ++i) nsum += (float)src_ns[i];
        atomicAdd(out, -0.5f * total / nsum);
    }
}

extern "C" void kernel_launch(void* const* d_in, const int* in_sizes, int n_in,
                              void* d_out, int out_size, void* d_ws, size_t ws_size,
                              hipStream_t stream)
{
    const float* pred   = (const float*)d_in[0];
    const float* gtp    = (const float*)d_in[1];
    const int*   src_ns = (const int*)d_in[2];
    const int*   tgt_ns = (const int*)d_in[3];
    const float* beta   = (const float*)d_in[4];
    float* out = (float*)d_out;
    float* ws  = (float*)d_ws;

    // zeroed region first: [col_gt][col_cnt][tgt_neg][nnz][flag]
    float* col_gt  = ws;
    float* col_cnt = col_gt  + B_ * M_;
    float* tgt_neg = col_cnt + B_ * M_;
    int*   nnz     = (int*)(tgt_neg + B_ * M_);
    int*   flag    = nnz + B_ * N_;
    float* src_neg = (float*)(flag + 1);
    float* src_pos = src_neg + B_ * N_;
    int*   ent_col = (int*)(src_pos + B_ * N_);
    float* ent_val = (float*)(ent_col + B_ * N_ * KCAP);

    const size_t zero_bytes = (size_t)(3 * B_ * M_ + B_ * N_ + 1) * sizeof(float);
    hipMemsetAsync(d_ws, 0, zero_bytes, stream);
    hipMemsetAsync(d_out, 0, sizeof(float), stream);

    dim3 grid(N_ / ROWS, B_);
    k_pass1<<<grid, 256, 0, stream>>>(pred, gtp, src_ns, tgt_ns, beta,
                                      col_gt, col_cnt, src_neg, src_pos,
                                      nnz, ent_col, ent_val, flag);
    k_pass2<<<grid, 256, 0, stream>>>(pred, gtp, src_ns, tgt_ns, beta,
                                      col_gt, col_cnt, nnz, ent_col, ent_val, flag,
                                      tgt_neg);
    k_final<<<B_, 256, 0, stream>>>(src_neg, src_pos, tgt_neg, col_cnt, src_ns, out);
}